// Round 3
// baseline (90.384 us; speedup 1.0000x reference)
//
#include <hip/hip_runtime.h>
#include <math.h>

#define NMAX   64
#define NSITES 12
#define SPLIT  4      // threads per batch element (3 sites each)
#define BLOCK  256
#define RS     68     // LDS row stride (floats): rows 16B-aligned; the 4
                      // site rows read per wave-op start at banks
                      // {0,12,24,4} -> disjoint b128 spans, conflict-free

#define B_SOFT 0.01f
#define PAD_C  4.0e4f   // sentinel coord -> r ~ 5.7e4 -> exp(-r) == 0.0f
                        // -> contributes exactly 0; no clamp needed

#define NB_FLOATS (NSITES * RS)     // 816 floats per coord array
#define WS_F      (2 * NB_FLOATS)   // device-global scratch (nbx | nby)

__device__ __align__(16) float g_ws[WS_F];
__device__ int g_m;

typedef float v4f __attribute__((ext_vector_type(4)));

// One block: ballot-compact neighbor lists into SoA (~64 -> ~58) once.
__global__ void init_kernel(const float* __restrict__ neighbors,
                            const float* __restrict__ mask) {
    __shared__ int cnt[NSITES];
    const int tid  = threadIdx.x;
    const int wv   = tid >> 6;
    const int lane = tid & 63;

    for (int i = tid; i < WS_F; i += BLOCK) g_ws[i] = PAD_C;
    __syncthreads();

    for (int s = wv; s < NSITES; s += 4) {
        const bool keep = mask[s * NMAX + lane] > 0.5f;
        const unsigned long long bal = __ballot(keep);
        if (keep) {
            const int pos = __popcll(bal & ((1ull << lane) - 1ull));
            const float2 p = ((const float2*)neighbors)[s * NMAX + lane];
            g_ws[s * RS + pos]             = p.x;
            g_ws[NB_FLOATS + s * RS + pos] = p.y;
        }
        if (lane == 0) cnt[s] = __popcll(bal);
    }
    __syncthreads();
    if (tid == 0) {
        int m = 0;
        #pragma unroll
        for (int s = 0; s < NSITES; ++s) m = max(m, cnt[s]);
        g_m = (m + 3) & ~3;   // <= 64, RS-safe
    }
}

__global__ __launch_bounds__(BLOCK, 8)
void pot_energy_kernel(const float* __restrict__ x,
                       float* __restrict__ out, int B) {
    __shared__ __align__(16) float smem[WS_F];   // 6528 B -> 8 blocks/CU
    const int tid = threadIdx.x;

    // Lean prologue: copy compacted neighbor rows from L2-hot global.
    {
        const float4* s4 = (const float4*)g_ws;
        float4* d4 = (float4*)smem;
        #pragma unroll
        for (int i = 0; i < 2; ++i) {
            const int idx = tid + i * BLOCK;
            if (idx < WS_F / 4) d4[idx] = s4[idx];
        }
    }
    const int m = g_m;          // uniform -> scalar load
    __syncthreads();

    const int gtid = blockIdx.x * BLOCK + tid;
    const int e = gtid >> 2;
    const int q = gtid & 3;
    if (e >= B) return;

    const float2* xp = (const float2*)(x + (size_t)gtid * 6);
    const float2 p0 = xp[0], p1 = xp[1], p2 = xp[2];
    const float xs_[3] = { p0.x, p1.x, p2.x };
    const float ys_[3] = { p0.y, p1.y, p2.y };

    const float NLOG2E = -1.4426950408889634f;   // -log2(e)

    float acc0 = 0.f, acc1 = 0.f;   // 2 fma chains for ILP
    #pragma unroll
    for (int s = 0; s < 3; ++s) {
        const int site = q * 3 + s;
        const float xs = xs_[s];
        const float ys = ys_[s];
        const float* __restrict__ rx = smem + site * RS;
        const float* __restrict__ ry = rx + NB_FLOATS;
        #pragma unroll 2
        for (int j0 = 0; j0 < m; j0 += 4) {
            const v4f nx4 = *(const v4f*)(rx + j0);   // ds_read_b128, 4-addr
            const v4f ny4 = *(const v4f*)(ry + j0);   // broadcast, no conflict
            const float nx[4] = { nx4.x, nx4.y, nx4.z, nx4.w };
            const float ny[4] = { ny4.x, ny4.y, ny4.z, ny4.w };
            #pragma unroll
            for (int k = 0; k < 4; ++k) {
                const float dx = xs - nx[k];
                const float dy = ys - ny[k];
                const float r2 = fmaf(dy, dy, dx * dx);
                // direct eval: v_sqrt + v_exp + v_rcp (trans pipe),
                // no table gather, no clamping (sentinel -> exp==0)
                const float r  = __builtin_amdgcn_sqrtf(r2);
                const float ex = __builtin_amdgcn_exp2f(r * NLOG2E);
                const float rc = __builtin_amdgcn_rcpf(r + B_SOFT);
                if (k & 1) acc1 = fmaf(ex, rc, acc1);
                else       acc0 = fmaf(ex, rc, acc0);
            }
        }
    }

    float acc = acc0 + acc1;
    acc += __shfl_xor(acc, 1);   // combine the 4 partials of element e
    acc += __shfl_xor(acc, 2);
    if (q == 0) out[e] = acc;
}

extern "C" void kernel_launch(void* const* d_in, const int* in_sizes, int n_in,
                              void* d_out, int out_size, void* d_ws, size_t ws_size,
                              hipStream_t stream) {
    const float* x   = (const float*)d_in[0];
    const float* nbr = (const float*)d_in[1];
    const float* msk = (const float*)d_in[2];
    float* out = (float*)d_out;

    const int B = in_sizes[0] / 24;

    init_kernel<<<1, BLOCK, 0, stream>>>(nbr, msk);

    const int total_threads = B * SPLIT;
    const int blocks = (total_threads + BLOCK - 1) / BLOCK;
    pot_energy_kernel<<<blocks, BLOCK, 0, stream>>>(x, out, B);
}

// Round 4
// 80.650 us; speedup vs baseline: 1.1207x; 1.1207x over previous
//
#include <hip/hip_runtime.h>
#include <math.h>

#define NMAX   64
#define NSITES 12
#define BLOCK  256
#define EPB    64     // elements per block: one per lane; wave w owns sites 3w..3w+2
#define RS     68     // neighbor row stride (floats), 16B-aligned rows

#define B_SOFT 0.01f
#define PAD_C  14.0f  // sentinel coord: r2 in [~155,~740] -> f ~ 3e-7, inside table
#define TBL_LO 1392   // (bits>>19) of 2^-40
#define TBL_N  800    // 16 bins/octave, r2 in [2^-40, 2^10); real r2 <= ~233
#define RAW_LO (TBL_LO * 8)   // 11136 = low bound of (bits>>16)&~7

#define NB_F   (NSITES * RS)          // 816
#define GW_NBX (2 * TBL_N)            // 1600
#define GW_NBY (GW_NBX + NB_F)        // 2416
#define GW_F   (GW_NBY + NB_F)        // 3232 floats

// LDS float layout: table [0,1600) | nbx [1600,2416) | nby [2416,3232) | part
#define L_NBX  (2 * TBL_N)
#define L_NBY  (L_NBX + NB_F)
#define L_PART (L_NBY + NB_F)
#define SMEM_F (L_PART + 3 * EPB)     // 3424 floats = 13696 B -> 8 blocks/CU

__device__ __align__(16) float g_ws[GW_F];
__device__ int g_mq[4];

typedef float v2f __attribute__((ext_vector_type(2)));
typedef float v4f __attribute__((ext_vector_type(4)));

// f(r2) = exp(-sqrt(r2)) / (sqrt(r2) + b), exact (init kernel only)
__device__ __forceinline__ float f_exact(float r2) {
    const float r = sqrtf(r2);
    return expf(-r) / (r + B_SOFT);
}

// One block, once per launch: build lerp table + ballot-compact neighbors.
__global__ void init_kernel(const float* __restrict__ neighbors,
                            const float* __restrict__ mask) {
    __shared__ int cnt[NSITES];
    const int tid  = threadIdx.x;
    const int wv   = tid >> 6;
    const int lane = tid & 63;

    // Piecewise-linear table: bin i covers r2-bits [ (i+LO)<<19, (i+LO+1)<<19 );
    // chord + midpoint correction halves the max lerp error.
    for (int i = tid; i < TBL_N; i += BLOCK) {
        const unsigned ii = (unsigned)(i + TBL_LO);
        const float b0 = __builtin_bit_cast(float, ii << 19);
        const float b1 = __builtin_bit_cast(float, (ii + 1u) << 19);
        const float f0 = f_exact(b0);
        const float f1 = f_exact(b1);
        const float fm = f_exact(0.5f * (b0 + b1));
        const float sl = (f1 - f0) / (b1 - b0);
        const float c  = f0 - sl * b0 - 0.5f * (0.5f * (f0 + f1) - fm);
        g_ws[2 * i]     = c;
        g_ws[2 * i + 1] = sl;
    }

    // Sentinel fill: slots past a site's count -> r2 in [155,740] -> f~3e-7.
    for (int i = tid; i < 2 * NB_F; i += BLOCK) g_ws[GW_NBX + i] = PAD_C;
    __syncthreads();

    for (int s = wv; s < NSITES; s += 4) {
        const bool keep = mask[s * NMAX + lane] > 0.5f;
        const unsigned long long bal = __ballot(keep);
        if (keep) {
            const int pos = __popcll(bal & ((1ull << lane) - 1ull));
            const float2 p = ((const float2*)neighbors)[s * NMAX + lane];
            g_ws[GW_NBX + s * RS + pos] = p.x;
            g_ws[GW_NBY + s * RS + pos] = p.y;
        }
        if (lane == 0) cnt[s] = __popcll(bal);
    }
    __syncthreads();
    if (tid < 4) {    // per-wave loop bound: max over that wave's 3 sites
        const int mm = max(cnt[3 * tid],
                       max(cnt[3 * tid + 1], cnt[3 * tid + 2]));
        g_mq[tid] = (mm + 3) & ~3;   // <= 64, RS-safe
    }
}

__global__ __launch_bounds__(BLOCK, 8)
void pot_energy_kernel(const float* __restrict__ x,
                       float* __restrict__ out, int B) {
    __shared__ __align__(16) float smem[SMEM_F];
    const int tid  = threadIdx.x;
    const int w    = tid >> 6;     // wave = site-quadrant (uniform per wave)
    const int lane = tid & 63;     // lane = element within the block

    // Prologue: copy table + compacted neighbors from L2-hot device global.
    {
        const float4* s4 = (const float4*)g_ws;
        float4* d4 = (float4*)smem;
        #pragma unroll
        for (int i0 = 0; i0 < 4; ++i0) {
            const int i = tid + i0 * BLOCK;
            if (i < GW_F / 4) d4[i] = s4[i];
        }
    }
    const int q = __builtin_amdgcn_readfirstlane(w);
    const int m = g_mq[q];         // wave-uniform -> scalar load
    __syncthreads();

    const int e  = blockIdx.x * EPB + lane;
    const int el = (e < B) ? e : 0;

    // This wave's 3 site positions for element e: 6 contiguous floats.
    const float* xb = x + (size_t)el * 24 + q * 6;
    const float2 pa = ((const float2*)xb)[0];
    const float2 pb = ((const float2*)xb)[1];
    const float2 pc = ((const float2*)xb)[2];
    const float xs_[3] = { pa.x, pb.x, pc.x };
    const float ys_[3] = { pa.y, pb.y, pc.y };

    const char* tb = (const char*)smem - RAW_LO;   // tb + raw indexes table
    const v2f eps2 = { 9.094947e-13f, 9.094947e-13f };   // 2^-40 floor, in-fma

    float accC = 0.f, accS = 0.f;   // sum(c_i) and sum(s_i * r2_i)
    #pragma unroll
    for (int s = 0; s < 3; ++s) {
        const int site = q * 3 + s;
        // All 64 lanes read the SAME address -> pure broadcast, conflict-free.
        const float* __restrict__ rx = smem + L_NBX + site * RS;
        const float* __restrict__ ry = smem + L_NBY + site * RS;
        const v2f xs2 = { xs_[s], xs_[s] };
        const v2f ys2 = { ys_[s], ys_[s] };
        #pragma unroll 2
        for (int j0 = 0; j0 < m; j0 += 4) {
            const v4f nx4 = *(const v4f*)(rx + j0);
            const v4f ny4 = *(const v4f*)(ry + j0);
            const v2f dxA = xs2 - nx4.xy;
            const v2f dxB = xs2 - nx4.zw;
            const v2f dyA = ys2 - ny4.xy;
            const v2f dyB = ys2 - ny4.zw;
            // eps folded into the fma chain: r2 >= 2^-40, no low clamp op
            const v2f r2A = __builtin_elementwise_fma(
                dyA, dyA, __builtin_elementwise_fma(dxA, dxA, eps2));
            const v2f r2B = __builtin_elementwise_fma(
                dyB, dyB, __builtin_elementwise_fma(dxB, dxB, eps2));
            const float r2k[4] = { r2A.x, r2A.y, r2B.x, r2B.y };
            #pragma unroll
            for (int k = 0; k < 4; ++k) {
                // no upper clamp: real r2 <= ~233, sentinel <= ~740, table
                // covers to 1024. Same-neighbor-across-lanes -> r2 clusters
                // into few bins -> same-address broadcasts -> cheap gather.
                const unsigned raw =
                    (__builtin_bit_cast(unsigned, r2k[k]) >> 16) & 0xFFF8u;
                const float2 cs = *(const float2*)(tb + raw);
                accC += cs.x;
                accS = fmaf(cs.y, r2k[k], accS);
            }
        }
    }

    // Combine the 4 wave-partials of each element via LDS.
    const float av = accC + accS;
    if (w != 0) smem[L_PART + (w - 1) * EPB + lane] = av;
    __syncthreads();
    if (w == 0 && e < B) {
        out[e] = av + smem[L_PART + lane]
                    + smem[L_PART + EPB + lane]
                    + smem[L_PART + 2 * EPB + lane];   // coalesced store
    }
}

extern "C" void kernel_launch(void* const* d_in, const int* in_sizes, int n_in,
                              void* d_out, int out_size, void* d_ws, size_t ws_size,
                              hipStream_t stream) {
    const float* x   = (const float*)d_in[0];
    const float* nbr = (const float*)d_in[1];
    const float* msk = (const float*)d_in[2];
    float* out = (float*)d_out;

    const int B = in_sizes[0] / 24;

    init_kernel<<<1, BLOCK, 0, stream>>>(nbr, msk);

    const int blocks = (B + EPB - 1) / EPB;
    pot_energy_kernel<<<blocks, BLOCK, 0, stream>>>(x, out, B);
}